// Round 1
// baseline (1453.084 us; speedup 1.0000x reference)
//
#include <hip/hip_runtime.h>
#include <hip/hip_bf16.h>

#define N_NODES 50000
#define N_EDGES 800000

typedef short s16x8 __attribute__((ext_vector_type(8)));
typedef short s16x4 __attribute__((ext_vector_type(4)));
typedef float f32x4 __attribute__((ext_vector_type(4)));

__device__ __forceinline__ unsigned short f2bf(float f) {
    union { float f; unsigned u; } v; v.f = f;
    unsigned r = v.u + 0x7fffu + ((v.u >> 16) & 1u);
    return (unsigned short)(r >> 16);
}

__device__ __forceinline__ s16x8 ld8(const unsigned short* p) {
    return *(const s16x8*)p;
}

__device__ __forceinline__ float elu(float h) {
    return h > 0.0f ? h : (__expf(h) - 1.0f);
}

// dst[n*K + k] = bf16(src[k*N + n])   (transpose + convert)
__global__ void wconv_kernel(const float* __restrict__ src,
                             unsigned short* __restrict__ dst,
                             int K, int N) {
    int idx = blockIdx.x * 256 + threadIdx.x;
    if (idx >= K * N) return;
    int n = idx / K;
    int k = idx - n * K;
    dst[idx] = f2bf(src[k * N + n]);
}

#define EP 264  // edge LDS pitch in bf16 elems (256 + 8 pad -> 528B rows, 2-way bank alias only)

__global__ __launch_bounds__(256, 3) void edge_kernel(
    const float* __restrict__ x, const int* __restrict__ ei,
    const float* __restrict__ ea,
    const float* __restrict__ b1a, const float* __restrict__ b1b,
    const unsigned short* __restrict__ w1aT, const unsigned short* __restrict__ w1bT,
    float* __restrict__ sums, float* __restrict__ cnt)
{
    __shared__ unsigned short lA[64 * EP];
    __shared__ int lrow[64];
    __shared__ int lcol[64];
    const int t = threadIdx.x;
    const int e0 = blockIdx.x * 64;

    if (t < 64) {
        lrow[t] = ei[e0 + t];
        lcol[t] = ei[N_EDGES + e0 + t];
    }
    __syncthreads();

    // edge-count atomics (each edge exactly once across grid)
    if (t < 64) atomicAdd(&cnt[lcol[t]], 1.0f);

    // stage A = concat(x[row], edge_attr) as bf16 into LDS
    const f32x4* x4 = (const f32x4*)x;
    const f32x4* ea4 = (const f32x4*)ea;
#pragma unroll
    for (int i = 0; i < 8; i++) {
        int idx = i * 256 + t, r = idx >> 5, c4 = idx & 31;
        f32x4 v = x4[lrow[r] * 32 + c4];
        s16x4 b = { (short)f2bf(v.x), (short)f2bf(v.y), (short)f2bf(v.z), (short)f2bf(v.w) };
        *(s16x4*)&lA[r * EP + c4 * 4] = b;
    }
#pragma unroll
    for (int i = 0; i < 8; i++) {
        int idx = i * 256 + t, r = idx >> 5, c4 = idx & 31;
        f32x4 v = ea4[(e0 + r) * 32 + c4];
        s16x4 b = { (short)f2bf(v.x), (short)f2bf(v.y), (short)f2bf(v.z), (short)f2bf(v.w) };
        *(s16x4*)&lA[r * EP + 128 + c4 * 4] = b;
    }
    __syncthreads();

    const int wv = t >> 6, lane = t & 63;
    const int quad = lane >> 4, l15 = lane & 15;

    f32x4 acc[4][4];
#pragma unroll
    for (int m = 0; m < 4; m++)
#pragma unroll
        for (int n = 0; n < 4; n++)
            acc[m][n] = (f32x4){0.f, 0.f, 0.f, 0.f};

    // layer 1: K = 256
    for (int kk = 0; kk < 8; kk++) {
        s16x8 a[4], b[4];
#pragma unroll
        for (int m = 0; m < 4; m++)
            a[m] = *(const s16x8*)&lA[(m * 16 + l15) * EP + kk * 32 + quad * 8];
#pragma unroll
        for (int n = 0; n < 4; n++)
            b[n] = ld8(&w1aT[(wv * 64 + n * 16 + l15) * 256 + kk * 32 + quad * 8]);
#pragma unroll
        for (int m = 0; m < 4; m++)
#pragma unroll
            for (int n = 0; n < 4; n++)
                acc[m][n] = __builtin_amdgcn_mfma_f32_16x16x32_bf16(a[m], b[n], acc[m][n], 0, 0, 0);
    }

    __syncthreads();  // all lA reads done before overwrite with H

    // ELU epilogue -> H (bf16) back into lA
#pragma unroll
    for (int m = 0; m < 4; m++)
#pragma unroll
        for (int n = 0; n < 4; n++) {
            int col = wv * 64 + n * 16 + l15;
            float bias = b1a[col];
#pragma unroll
            for (int v = 0; v < 4; v++) {
                int row = m * 16 + quad * 4 + v;
                float h = elu(acc[m][n][v] + bias);
                lA[row * EP + col] = f2bf(h);
            }
            acc[m][n] = (f32x4){0.f, 0.f, 0.f, 0.f};
        }
    __syncthreads();

    // layer 2: K = 256
    for (int kk = 0; kk < 8; kk++) {
        s16x8 a[4], b[4];
#pragma unroll
        for (int m = 0; m < 4; m++)
            a[m] = *(const s16x8*)&lA[(m * 16 + l15) * EP + kk * 32 + quad * 8];
#pragma unroll
        for (int n = 0; n < 4; n++)
            b[n] = ld8(&w1bT[(wv * 64 + n * 16 + l15) * 256 + kk * 32 + quad * 8]);
#pragma unroll
        for (int m = 0; m < 4; m++)
#pragma unroll
            for (int n = 0; n < 4; n++)
                acc[m][n] = __builtin_amdgcn_mfma_f32_16x16x32_bf16(a[m], b[n], acc[m][n], 0, 0, 0);
    }

    // scatter-add into sums
#pragma unroll
    for (int m = 0; m < 4; m++)
#pragma unroll
        for (int n = 0; n < 4; n++) {
            int col = wv * 64 + n * 16 + l15;
            float bias = b1b[col];
#pragma unroll
            for (int v = 0; v < 4; v++) {
                int row = m * 16 + quad * 4 + v;
                float h = acc[m][n][v] + bias;
                atomicAdd(&sums[lcol[row] * 256 + col], h);
            }
        }
}

#define NP 392  // node LDS pitch in bf16 elems (384 + 8 pad)

__global__ __launch_bounds__(256, 3) void node_kernel(
    const float* __restrict__ x, const float* __restrict__ sums,
    const float* __restrict__ cnt,
    const float* __restrict__ b2a, const float* __restrict__ b2b,
    const unsigned short* __restrict__ w2aT, const unsigned short* __restrict__ w2bT,
    float* __restrict__ out)
{
    __shared__ unsigned short lA[64 * NP];
    __shared__ float linv[64];
    const int t = threadIdx.x;
    const int n0 = blockIdx.x * 64;

    if (t < 64) {
        float c = 1.0f;
        if (n0 + t < N_NODES) c = cnt[n0 + t];
        linv[t] = 1.0f / fmaxf(c, 1.0f);
    }
    __syncthreads();

    // stage z = concat(x, mean) as bf16
#pragma unroll
    for (int i = 0; i < 8; i++) {
        int idx = i * 256 + t, r = idx >> 5, c4 = idx & 31;
        int node = n0 + r;
        f32x4 v = {0.f, 0.f, 0.f, 0.f};
        if (node < N_NODES) v = ((const f32x4*)x)[node * 32 + c4];
        s16x4 b = { (short)f2bf(v.x), (short)f2bf(v.y), (short)f2bf(v.z), (short)f2bf(v.w) };
        *(s16x4*)&lA[r * NP + c4 * 4] = b;
    }
#pragma unroll
    for (int i = 0; i < 16; i++) {
        int idx = i * 256 + t, r = idx >> 6, c4 = idx & 63;
        int node = n0 + r;
        f32x4 v = {0.f, 0.f, 0.f, 0.f};
        if (node < N_NODES) v = ((const f32x4*)sums)[node * 64 + c4];
        float s = linv[r];
        s16x4 b = { (short)f2bf(v.x * s), (short)f2bf(v.y * s),
                    (short)f2bf(v.z * s), (short)f2bf(v.w * s) };
        *(s16x4*)&lA[r * NP + 128 + c4 * 4] = b;
    }
    __syncthreads();

    const int wv = t >> 6, lane = t & 63;
    const int quad = lane >> 4, l15 = lane & 15;

    f32x4 acc[4][4];
#pragma unroll
    for (int m = 0; m < 4; m++)
#pragma unroll
        for (int n = 0; n < 4; n++)
            acc[m][n] = (f32x4){0.f, 0.f, 0.f, 0.f};

    // layer a: K = 384
    for (int kk = 0; kk < 12; kk++) {
        s16x8 a[4], b[4];
#pragma unroll
        for (int m = 0; m < 4; m++)
            a[m] = *(const s16x8*)&lA[(m * 16 + l15) * NP + kk * 32 + quad * 8];
#pragma unroll
        for (int n = 0; n < 4; n++)
            b[n] = ld8(&w2aT[(wv * 64 + n * 16 + l15) * 384 + kk * 32 + quad * 8]);
#pragma unroll
        for (int m = 0; m < 4; m++)
#pragma unroll
            for (int n = 0; n < 4; n++)
                acc[m][n] = __builtin_amdgcn_mfma_f32_16x16x32_bf16(a[m], b[n], acc[m][n], 0, 0, 0);
    }

    __syncthreads();

#pragma unroll
    for (int m = 0; m < 4; m++)
#pragma unroll
        for (int n = 0; n < 4; n++) {
            int col = wv * 64 + n * 16 + l15;
            float bias = b2a[col];
#pragma unroll
            for (int v = 0; v < 4; v++) {
                int row = m * 16 + quad * 4 + v;
                float h = elu(acc[m][n][v] + bias);
                lA[row * NP + col] = f2bf(h);
            }
            acc[m][n] = (f32x4){0.f, 0.f, 0.f, 0.f};
        }
    __syncthreads();

    // layer b: K = 256
    for (int kk = 0; kk < 8; kk++) {
        s16x8 a[4], b[4];
#pragma unroll
        for (int m = 0; m < 4; m++)
            a[m] = *(const s16x8*)&lA[(m * 16 + l15) * NP + kk * 32 + quad * 8];
#pragma unroll
        for (int n = 0; n < 4; n++)
            b[n] = ld8(&w2bT[(wv * 64 + n * 16 + l15) * 256 + kk * 32 + quad * 8]);
#pragma unroll
        for (int m = 0; m < 4; m++)
#pragma unroll
            for (int n = 0; n < 4; n++)
                acc[m][n] = __builtin_amdgcn_mfma_f32_16x16x32_bf16(a[m], b[n], acc[m][n], 0, 0, 0);
    }

#pragma unroll
    for (int m = 0; m < 4; m++)
#pragma unroll
        for (int n = 0; n < 4; n++) {
            int col = wv * 64 + n * 16 + l15;
            float bias = b2b[col];
#pragma unroll
            for (int v = 0; v < 4; v++) {
                int row = m * 16 + quad * 4 + v;
                int node = n0 + row;
                if (node < N_NODES)
                    out[node * 256 + col] = acc[m][n][v] + bias;
            }
        }
}

// ---- workspace layout (bytes) ----
#define WS_SUMS 0u
#define WS_CNT  51200000u
#define WS_ZERO_BYTES 51400000u   // sums + cnt
#define WS_W1A  51400000u
#define WS_W1B  51531072u
#define WS_W2A  51662144u
#define WS_W2B  51858752u

extern "C" void kernel_launch(void* const* d_in, const int* in_sizes, int n_in,
                              void* d_out, int out_size, void* d_ws, size_t ws_size,
                              hipStream_t stream) {
    const float* x   = (const float*)d_in[0];
    const int*   ei  = (const int*)d_in[1];
    const float* ea  = (const float*)d_in[2];
    // d_in[3] = u, d_in[4] = batch: unused by the reference computation
    const float* w1a = (const float*)d_in[5];
    const float* b1a = (const float*)d_in[6];
    const float* w1b = (const float*)d_in[7];
    const float* b1b = (const float*)d_in[8];
    const float* w2a = (const float*)d_in[9];
    const float* b2a = (const float*)d_in[10];
    const float* w2b = (const float*)d_in[11];
    const float* b2b = (const float*)d_in[12];
    float* out = (float*)d_out;

    char* ws = (char*)d_ws;
    float* sums = (float*)(ws + WS_SUMS);
    float* cnt  = (float*)(ws + WS_CNT);
    unsigned short* w1aT = (unsigned short*)(ws + WS_W1A);
    unsigned short* w1bT = (unsigned short*)(ws + WS_W1B);
    unsigned short* w2aT = (unsigned short*)(ws + WS_W2A);
    unsigned short* w2bT = (unsigned short*)(ws + WS_W2B);

    hipMemsetAsync(d_ws, 0, WS_ZERO_BYTES, stream);

    wconv_kernel<<<(256 * 256 + 255) / 256, 256, 0, stream>>>(w1a, w1aT, 256, 256);
    wconv_kernel<<<(256 * 256 + 255) / 256, 256, 0, stream>>>(w1b, w1bT, 256, 256);
    wconv_kernel<<<(384 * 256 + 255) / 256, 256, 0, stream>>>(w2a, w2aT, 384, 256);
    wconv_kernel<<<(256 * 256 + 255) / 256, 256, 0, stream>>>(w2b, w2bT, 256, 256);

    edge_kernel<<<N_EDGES / 64, 256, 0, stream>>>(x, ei, ea, b1a, b1b, w1aT, w1bT, sums, cnt);

    node_kernel<<<(N_NODES + 63) / 64, 256, 0, stream>>>(x, sums, cnt, b2a, b2b, w2aT, w2bT, out);
}

// Round 2
// 976.498 us; speedup vs baseline: 1.4881x; 1.4881x over previous
//
#include <hip/hip_runtime.h>
#include <hip/hip_bf16.h>

#define N_NODES 50000
#define N_EDGES 800000

typedef short s16x8 __attribute__((ext_vector_type(8)));
typedef short s16x4 __attribute__((ext_vector_type(4)));
typedef float f32x4 __attribute__((ext_vector_type(4)));

__device__ __forceinline__ unsigned short f2bf(float f) {
    union { float f; unsigned u; } v; v.f = f;
    unsigned r = v.u + 0x7fffu + ((v.u >> 16) & 1u);
    return (unsigned short)(r >> 16);
}

__device__ __forceinline__ float bf2f(unsigned short u) {
    union { unsigned u; float f; } v; v.u = ((unsigned)u) << 16;
    return v.f;
}

__device__ __forceinline__ s16x8 ld8(const unsigned short* p) {
    return *(const s16x8*)p;
}

__device__ __forceinline__ float elu(float h) {
    return h > 0.0f ? h : (__expf(h) - 1.0f);
}

// dst[n*K + k] = bf16(src[k*N + n])   (transpose + convert)
__global__ void wconv_kernel(const float* __restrict__ src,
                             unsigned short* __restrict__ dst,
                             int K, int N) {
    int idx = blockIdx.x * 256 + threadIdx.x;
    if (idx >= K * N) return;
    int n = idx / K;
    int k = idx - n * K;
    dst[idx] = f2bf(src[k * N + n]);
}

// histogram of destination nodes (doubles as cnt)
__global__ void hist_kernel(const int* __restrict__ ei, int* __restrict__ hist) {
    int e = blockIdx.x * 256 + threadIdx.x;
    if (e < N_EDGES) atomicAdd(&hist[ei[N_EDGES + e]], 1);
}

// single-block exclusive scan of hist[50000] -> cursor[50000]
__global__ void scan_kernel(const int* __restrict__ hist, int* __restrict__ cursor) {
    __shared__ int tmp[1024];
    __shared__ int carryS;
    const int t = threadIdx.x;
    if (t == 0) carryS = 0;
    __syncthreads();
    for (int base = 0; base < N_NODES; base += 4096) {
        int i = base + t * 4;
        int4 v = {0, 0, 0, 0};
        if (i + 3 < N_NODES) v = *(const int4*)&hist[i];
        else {
            v.x = (i + 0 < N_NODES) ? hist[i + 0] : 0;
            v.y = (i + 1 < N_NODES) ? hist[i + 1] : 0;
            v.z = (i + 2 < N_NODES) ? hist[i + 2] : 0;
            v.w = (i + 3 < N_NODES) ? hist[i + 3] : 0;
        }
        int s = v.x + v.y + v.z + v.w;
        tmp[t] = s;
        __syncthreads();
        for (int off = 1; off < 1024; off <<= 1) {
            int add = (t >= off) ? tmp[t - off] : 0;
            __syncthreads();
            tmp[t] += add;
            __syncthreads();
        }
        int incl = tmp[t];
        int excl0 = carryS + incl - s;
        if (i     < N_NODES) cursor[i]     = excl0;
        if (i + 1 < N_NODES) cursor[i + 1] = excl0 + v.x;
        if (i + 2 < N_NODES) cursor[i + 2] = excl0 + v.x + v.y;
        if (i + 3 < N_NODES) cursor[i + 3] = excl0 + v.x + v.y + v.z;
        __syncthreads();
        if (t == 1023) carryS += incl;
        __syncthreads();
    }
}

// scatter edge ids into destination-sorted order
__global__ void scatter_kernel(const int* __restrict__ ei, int* __restrict__ cursor,
                               int* __restrict__ sidx) {
    int e = blockIdx.x * 256 + threadIdx.x;
    if (e >= N_EDGES) return;
    int c = ei[N_EDGES + e];
    int p = atomicAdd(&cursor[c], 1);
    sidx[p] = e;
}

#define EP 264  // edge LDS pitch in bf16 elems (256 + 8 pad)

// layer-1 of edge MLP + ELU + block-local segmented reduction + atomic scatter
__global__ __launch_bounds__(256, 4) void edge_kernel(
    const float* __restrict__ x, const int* __restrict__ ei,
    const float* __restrict__ ea, const int* __restrict__ sidx,
    const float* __restrict__ b1a,
    const unsigned short* __restrict__ w1aT,
    float* __restrict__ sums)
{
    __shared__ unsigned short lA[64 * EP];
    __shared__ int lrow[64];
    __shared__ int lcol[64];
    __shared__ int lidx[64];
    __shared__ unsigned char segstart[64];
    const int t = threadIdx.x;
    const int e0 = blockIdx.x * 64;

    if (t < 64) {
        int idx = sidx[e0 + t];
        lidx[t] = idx;
        lrow[t] = ei[idx];
        lcol[t] = ei[N_EDGES + idx];
    }
    __syncthreads();
    if (t < 64) segstart[t] = (t == 0) ? 1 : (lcol[t] != lcol[t - 1]);

    // stage A = concat(x[row], edge_attr[idx]) as bf16 into LDS
    const f32x4* x4 = (const f32x4*)x;
    const f32x4* ea4 = (const f32x4*)ea;
#pragma unroll
    for (int i = 0; i < 8; i++) {
        int idx = i * 256 + t, r = idx >> 5, c4 = idx & 31;
        f32x4 v = x4[lrow[r] * 32 + c4];
        s16x4 b = { (short)f2bf(v.x), (short)f2bf(v.y), (short)f2bf(v.z), (short)f2bf(v.w) };
        *(s16x4*)&lA[r * EP + c4 * 4] = b;
    }
#pragma unroll
    for (int i = 0; i < 8; i++) {
        int idx = i * 256 + t, r = idx >> 5, c4 = idx & 31;
        f32x4 v = ea4[lidx[r] * 32 + c4];
        s16x4 b = { (short)f2bf(v.x), (short)f2bf(v.y), (short)f2bf(v.z), (short)f2bf(v.w) };
        *(s16x4*)&lA[r * EP + 128 + c4 * 4] = b;
    }
    __syncthreads();

    const int wv = t >> 6, lane = t & 63;
    const int quad = lane >> 4, l15 = lane & 15;

    f32x4 acc[4][4];
#pragma unroll
    for (int m = 0; m < 4; m++)
#pragma unroll
        for (int n = 0; n < 4; n++)
            acc[m][n] = (f32x4){0.f, 0.f, 0.f, 0.f};

    // layer 1: K = 256
    for (int kk = 0; kk < 8; kk++) {
        s16x8 a[4], b[4];
#pragma unroll
        for (int m = 0; m < 4; m++)
            a[m] = *(const s16x8*)&lA[(m * 16 + l15) * EP + kk * 32 + quad * 8];
#pragma unroll
        for (int n = 0; n < 4; n++)
            b[n] = ld8(&w1aT[(wv * 64 + n * 16 + l15) * 256 + kk * 32 + quad * 8]);
#pragma unroll
        for (int m = 0; m < 4; m++)
#pragma unroll
            for (int n = 0; n < 4; n++)
                acc[m][n] = __builtin_amdgcn_mfma_f32_16x16x32_bf16(a[m], b[n], acc[m][n], 0, 0, 0);
    }

    __syncthreads();  // all lA reads done before overwrite

    // ELU epilogue -> elu1 (bf16) back into lA cols 0..256
#pragma unroll
    for (int m = 0; m < 4; m++)
#pragma unroll
        for (int n = 0; n < 4; n++) {
            int col = wv * 64 + n * 16 + l15;
            float bias = b1a[col];
#pragma unroll
            for (int v = 0; v < 4; v++) {
                int row = m * 16 + quad * 4 + v;
                float h = elu(acc[m][n][v] + bias);
                lA[row * EP + col] = f2bf(h);
            }
        }
    __syncthreads();

    // segmented column reduction: thread t owns column t; edges sorted by col
    float s = 0.f;
    for (int r = 0; r < 64; r++) {
        if (r > 0 && segstart[r]) {
            atomicAdd(&sums[lcol[r - 1] * 256 + t], s);
            s = 0.f;
        }
        s += bf2f(lA[r * EP + t]);
    }
    atomicAdd(&sums[lcol[63] * 256 + t], s);
}

#define NP 392  // node LDS pitch in bf16 elems (384 + 8 pad)

// mean_elu@w1b(+b1b) -> concat(x, mean_h) -> w2a+ELU -> w2b+b2b
__global__ __launch_bounds__(256, 3) void node_kernel(
    const float* __restrict__ x, const float* __restrict__ sums,
    const int* __restrict__ hist,
    const float* __restrict__ b1b, const float* __restrict__ b2a,
    const float* __restrict__ b2b,
    const unsigned short* __restrict__ w1bT, const unsigned short* __restrict__ w2aT,
    const unsigned short* __restrict__ w2bT,
    float* __restrict__ out)
{
    __shared__ unsigned short lZ[64 * NP];
    __shared__ float linv[64];
    __shared__ unsigned char lpos[64];
    const int t = threadIdx.x;
    const int n0 = blockIdx.x * 64;

    if (t < 64) {
        int c = 0;
        if (n0 + t < N_NODES) c = hist[n0 + t];
        lpos[t] = (c > 0);
        linv[t] = 1.0f / fmaxf((float)c, 1.0f);
    }
    __syncthreads();

    // stage x -> cols 0..128 ; mean_elu -> cols 128..384
#pragma unroll
    for (int i = 0; i < 8; i++) {
        int idx = i * 256 + t, r = idx >> 5, c4 = idx & 31;
        int node = n0 + r;
        f32x4 v = {0.f, 0.f, 0.f, 0.f};
        if (node < N_NODES) v = ((const f32x4*)x)[node * 32 + c4];
        s16x4 b = { (short)f2bf(v.x), (short)f2bf(v.y), (short)f2bf(v.z), (short)f2bf(v.w) };
        *(s16x4*)&lZ[r * NP + c4 * 4] = b;
    }
#pragma unroll
    for (int i = 0; i < 16; i++) {
        int idx = i * 256 + t, r = idx >> 6, c4 = idx & 63;
        int node = n0 + r;
        f32x4 v = {0.f, 0.f, 0.f, 0.f};
        if (node < N_NODES) v = ((const f32x4*)sums)[node * 64 + c4];
        float sc = linv[r];
        s16x4 b = { (short)f2bf(v.x * sc), (short)f2bf(v.y * sc),
                    (short)f2bf(v.z * sc), (short)f2bf(v.w * sc) };
        *(s16x4*)&lZ[r * NP + 128 + c4 * 4] = b;
    }
    __syncthreads();

    const int wv = t >> 6, lane = t & 63;
    const int quad = lane >> 4, l15 = lane & 15;

    f32x4 acc[4][4];
#pragma unroll
    for (int m = 0; m < 4; m++)
#pragma unroll
        for (int n = 0; n < 4; n++)
            acc[m][n] = (f32x4){0.f, 0.f, 0.f, 0.f};

    // GEMM 1: mean_h = mean_elu @ w1b   (K = 256, A at col-offset 128)
    for (int kk = 0; kk < 8; kk++) {
        s16x8 a[4], b[4];
#pragma unroll
        for (int m = 0; m < 4; m++)
            a[m] = *(const s16x8*)&lZ[(m * 16 + l15) * NP + 128 + kk * 32 + quad * 8];
#pragma unroll
        for (int n = 0; n < 4; n++)
            b[n] = ld8(&w1bT[(wv * 64 + n * 16 + l15) * 256 + kk * 32 + quad * 8]);
#pragma unroll
        for (int m = 0; m < 4; m++)
#pragma unroll
            for (int n = 0; n < 4; n++)
                acc[m][n] = __builtin_amdgcn_mfma_f32_16x16x32_bf16(a[m], b[n], acc[m][n], 0, 0, 0);
    }
    __syncthreads();

    // epilogue 1: + b1b only where cnt>0 (reference gives exact 0 for isolated nodes)
#pragma unroll
    for (int m = 0; m < 4; m++)
#pragma unroll
        for (int n = 0; n < 4; n++) {
            int col = wv * 64 + n * 16 + l15;
            float bias = b1b[col];
#pragma unroll
            for (int v = 0; v < 4; v++) {
                int row = m * 16 + quad * 4 + v;
                float h = acc[m][n][v] + (lpos[row] ? bias : 0.f);
                lZ[row * NP + 128 + col] = f2bf(h);
            }
            acc[m][n] = (f32x4){0.f, 0.f, 0.f, 0.f};
        }
    __syncthreads();

    // GEMM 2: K = 384 over concat(x, mean_h)
    for (int kk = 0; kk < 12; kk++) {
        s16x8 a[4], b[4];
#pragma unroll
        for (int m = 0; m < 4; m++)
            a[m] = *(const s16x8*)&lZ[(m * 16 + l15) * NP + kk * 32 + quad * 8];
#pragma unroll
        for (int n = 0; n < 4; n++)
            b[n] = ld8(&w2aT[(wv * 64 + n * 16 + l15) * 384 + kk * 32 + quad * 8]);
#pragma unroll
        for (int m = 0; m < 4; m++)
#pragma unroll
            for (int n = 0; n < 4; n++)
                acc[m][n] = __builtin_amdgcn_mfma_f32_16x16x32_bf16(a[m], b[n], acc[m][n], 0, 0, 0);
    }
    __syncthreads();

    // epilogue 2: ELU -> H into lZ cols 0..256
#pragma unroll
    for (int m = 0; m < 4; m++)
#pragma unroll
        for (int n = 0; n < 4; n++) {
            int col = wv * 64 + n * 16 + l15;
            float bias = b2a[col];
#pragma unroll
            for (int v = 0; v < 4; v++) {
                int row = m * 16 + quad * 4 + v;
                float h = elu(acc[m][n][v] + bias);
                lZ[row * NP + col] = f2bf(h);
            }
            acc[m][n] = (f32x4){0.f, 0.f, 0.f, 0.f};
        }
    __syncthreads();

    // GEMM 3: K = 256
    for (int kk = 0; kk < 8; kk++) {
        s16x8 a[4], b[4];
#pragma unroll
        for (int m = 0; m < 4; m++)
            a[m] = *(const s16x8*)&lZ[(m * 16 + l15) * NP + kk * 32 + quad * 8];
#pragma unroll
        for (int n = 0; n < 4; n++)
            b[n] = ld8(&w2bT[(wv * 64 + n * 16 + l15) * 256 + kk * 32 + quad * 8]);
#pragma unroll
        for (int m = 0; m < 4; m++)
#pragma unroll
            for (int n = 0; n < 4; n++)
                acc[m][n] = __builtin_amdgcn_mfma_f32_16x16x32_bf16(a[m], b[n], acc[m][n], 0, 0, 0);
    }

#pragma unroll
    for (int m = 0; m < 4; m++)
#pragma unroll
        for (int n = 0; n < 4; n++) {
            int col = wv * 64 + n * 16 + l15;
            float bias = b2b[col];
#pragma unroll
            for (int v = 0; v < 4; v++) {
                int row = m * 16 + quad * 4 + v;
                int node = n0 + row;
                if (node < N_NODES)
                    out[node * 256 + col] = acc[m][n][v] + bias;
            }
        }
}

// ---- workspace layout (bytes) ----
#define WS_SUMS   0u
#define WS_HIST   51200000u
#define WS_ZERO_BYTES 51400000u   // sums + hist
#define WS_CURSOR 51400000u
#define WS_SIDX   51600000u
#define WS_W1A    54800000u
#define WS_W1B    54931072u
#define WS_W2A    55062144u
#define WS_W2B    55258752u

extern "C" void kernel_launch(void* const* d_in, const int* in_sizes, int n_in,
                              void* d_out, int out_size, void* d_ws, size_t ws_size,
                              hipStream_t stream) {
    const float* x   = (const float*)d_in[0];
    const int*   ei  = (const int*)d_in[1];
    const float* ea  = (const float*)d_in[2];
    const float* w1a = (const float*)d_in[5];
    const float* b1a = (const float*)d_in[6];
    const float* w1b = (const float*)d_in[7];
    const float* b1b = (const float*)d_in[8];
    const float* w2a = (const float*)d_in[9];
    const float* b2a = (const float*)d_in[10];
    const float* w2b = (const float*)d_in[11];
    const float* b2b = (const float*)d_in[12];
    float* out = (float*)d_out;

    char* ws = (char*)d_ws;
    float* sums = (float*)(ws + WS_SUMS);
    int* hist   = (int*)(ws + WS_HIST);
    int* cursor = (int*)(ws + WS_CURSOR);
    int* sidx   = (int*)(ws + WS_SIDX);
    unsigned short* w1aT = (unsigned short*)(ws + WS_W1A);
    unsigned short* w1bT = (unsigned short*)(ws + WS_W1B);
    unsigned short* w2aT = (unsigned short*)(ws + WS_W2A);
    unsigned short* w2bT = (unsigned short*)(ws + WS_W2B);

    hipMemsetAsync(d_ws, 0, WS_ZERO_BYTES, stream);

    wconv_kernel<<<(256 * 256 + 255) / 256, 256, 0, stream>>>(w1a, w1aT, 256, 256);
    wconv_kernel<<<(256 * 256 + 255) / 256, 256, 0, stream>>>(w1b, w1bT, 256, 256);
    wconv_kernel<<<(384 * 256 + 255) / 256, 256, 0, stream>>>(w2a, w2aT, 384, 256);
    wconv_kernel<<<(256 * 256 + 255) / 256, 256, 0, stream>>>(w2b, w2bT, 256, 256);

    hist_kernel<<<(N_EDGES + 255) / 256, 256, 0, stream>>>(ei, hist);
    scan_kernel<<<1, 1024, 0, stream>>>(hist, cursor);
    scatter_kernel<<<(N_EDGES + 255) / 256, 256, 0, stream>>>(ei, cursor, sidx);

    edge_kernel<<<N_EDGES / 64, 256, 0, stream>>>(x, ei, ea, sidx, b1a, w1aT, sums);

    node_kernel<<<(N_NODES + 63) / 64, 256, 0, stream>>>(x, sums, hist, b1b, b2a, b2b,
                                                         w1bT, w2aT, w2bT, out);
}